// Round 1
// baseline (362.851 us; speedup 1.0000x reference)
//
#include <hip/hip_runtime.h>
#include <math.h>

#define NN 50000
#define NNP 50048        // 391*128, padded row count for GEMM staging
#define NE 800000
#define NG 64
#define NBK 196          // buckets of 256 nodes
#define ECH 4082         // edges per hist/scatter block
#define TOTH (NBK * NBK) // 38416
#define NBH 151          // ceil(TOTH/256)
#define SBLK 6890        // setup blocks: (NN*32+163840)/256
#define SWORK (NN * 32 + 163840)
#define AGB 12500        // agg grid: 4 slices * (NN/16)

typedef __attribute__((ext_vector_type(8))) __bf16 bf16x8;
typedef __attribute__((ext_vector_type(4))) float f32x4;

__device__ inline unsigned short f2bf(float f) {
    unsigned int u = __float_as_uint(f);
    u += 0x7fffu + ((u >> 16) & 1u);   // round-to-nearest-even
    return (unsigned short)(u >> 16);
}
__device__ inline float bflo(unsigned int v) { return __uint_as_float(v << 16); }
__device__ inline float bfhi(unsigned int v) { return __uint_as_float(v & 0xffff0000u); }
__device__ inline float bfs(unsigned short v) { return __uint_as_float((unsigned int)v << 16); }

#define GLD_LDS16(g, l)                                                          \
    __builtin_amdgcn_global_load_lds(                                            \
        (const __attribute__((address_space(1))) unsigned int*)(g),              \
        (__attribute__((address_space(3))) unsigned int*)(l), 16, 0, 0)

// ------- front: x->bf16 + weight transposes + dst-histogram + bounds + out-zero ----
__global__ __launch_bounds__(256) void front_k(const float* __restrict__ x,
                                               const float* __restrict__ wr1,
                                               const float* __restrict__ wo1,
                                               const float* __restrict__ wr2,
                                               const float* __restrict__ wo2,
                                               const float* __restrict__ wr3,
                                               const float* __restrict__ wo3,
                                               const int* __restrict__ edst,
                                               const int* __restrict__ batch,
                                               unsigned short* __restrict__ xb,
                                               unsigned short* __restrict__ W1T,
                                               unsigned short* __restrict__ W2T,
                                               unsigned short* __restrict__ W3T,
                                               int* __restrict__ H,
                                               int* __restrict__ bounds,
                                               float* __restrict__ outp) {
    const int b = blockIdx.x, t = threadIdx.x;
    if (b < SBLK) {
        int id = b * 256 + t;
        if (id < NN * 32) {                       // x: 4 floats per thread
            float4 v = ((const float4*)x)[id];
            unsigned int p0 = ((unsigned int)f2bf(v.y) << 16) | f2bf(v.x);
            unsigned int p1 = ((unsigned int)f2bf(v.w) << 16) | f2bf(v.z);
            ((uint2*)xb)[id] = make_uint2(p0, p1);
            return;
        }
        int w = id - NN * 32;
        if (w < 32768) {
            int n = w >> 8, k = w & 255;
            W1T[w] = f2bf((k < 128) ? wr1[k * 128 + n] : wo1[(k - 128) * 128 + n]);
        } else if (w < 98304) {
            int j = w - 32768; int n = j >> 8, k = j & 255;
            W2T[j] = f2bf((k < 128) ? wr2[k * 256 + n] : wo2[(k - 128) * 256 + n]);
        } else if (w < 163840) {
            int j = w - 98304; int n = j >> 8, k = j & 255;
            W3T[j] = f2bf((n < 128) ? wr3[k * 128 + n] : wo3[k * 128 + (n - 128)]);
        }
        return;
    }
    if (b < SBLK + NBK) {                         // histogram chunk
        __shared__ int h[NBK];
        int k = b - SBLK;
        if (t < NBK) h[t] = 0;
        __syncthreads();
        int e0 = k * ECH, e1 = min(NE, e0 + ECH);
        for (int e = e0 + t; e < e1; e += 256) atomicAdd(&h[edst[e] >> 8], 1);
        __syncthreads();
        if (t < NBK) H[t * NBK + k] = h[t];       // bucket-major layout
        return;
    }
    // last block: graph bounds + zero output accumulator
    if (t <= NG) {
        int g = t, lo = 0, hi = NN;
        while (lo < hi) { int mid = (lo + hi) >> 1; if (batch[mid] < g) lo = mid + 1; else hi = mid; }
        bounds[g] = lo;
    }
    for (int i = t; i < NG * 128; i += 256) outp[i] = 0.f;
}

// ---------------- hierarchical scan of H ----------------
__global__ __launch_bounds__(256) void hsum_k(const int* __restrict__ H,
                                              int* __restrict__ hb) {
    int i = blockIdx.x * 256 + threadIdx.x;
    int v = (i < TOTH) ? H[i] : 0;
    for (int off = 32; off; off >>= 1) v += __shfl_xor(v, off, 64);
    __shared__ int ws[4];
    if ((threadIdx.x & 63) == 0) ws[threadIdx.x >> 6] = v;
    __syncthreads();
    if (threadIdx.x == 0) hb[blockIdx.x] = ws[0] + ws[1] + ws[2] + ws[3];
}

// folded: each block computes its own chunk offset (reduce hb[0..c)) + local scan
__global__ __launch_bounds__(256) void happly_k(const int* __restrict__ H,
                                                const int* __restrict__ hb,
                                                int* __restrict__ S) {
    __shared__ int s[256], ws[4], choff;
    const int t = threadIdx.x, c = blockIdx.x;
    {   // chunk offset = sum of hb[0..c)
        int v = (t < c) ? hb[t] : 0;              // c <= 150 < 256
        for (int off = 32; off; off >>= 1) v += __shfl_xor(v, off, 64);
        if ((t & 63) == 0) ws[t >> 6] = v;
        __syncthreads();
        if (t == 0) choff = ws[0] + ws[1] + ws[2] + ws[3];
        __syncthreads();
    }
    int i = c * 256 + t;
    int v = (i < TOTH) ? H[i] : 0;
    s[t] = v; __syncthreads();
    for (int off = 1; off < 256; off <<= 1) {
        int u = (t >= off) ? s[t - off] : 0;
        __syncthreads(); s[t] += u; __syncthreads();
    }
    if (i < TOTH) S[i] = choff + s[t] - v;
}

__global__ __launch_bounds__(256) void scatter_k(const int* __restrict__ src,
                                                 const int* __restrict__ dst,
                                                 const int* __restrict__ S,
                                                 int* __restrict__ tmp) {
    __shared__ int cur[NBK];
    int t = threadIdx.x, k = blockIdx.x;
    if (t < NBK) cur[t] = S[t * NBK + k];
    __syncthreads();
    int e0 = k * ECH, e1 = min(NE, e0 + ECH);
    for (int e = e0 + t; e < e1; e += 256) {
        int d = dst[e];
        int p = atomicAdd(&cur[d >> 8], 1);
        tmp[p] = ((d & 255) << 16) | src[e];
    }
}

__global__ __launch_bounds__(256) void csr_k(const int* __restrict__ tmp,
                                             const int* __restrict__ S,
                                             int* __restrict__ rowptr,
                                             int* __restrict__ colsrc) {
    __shared__ int hist[256], off[256], cur[256];
    int t = threadIdx.x, b = blockIdx.x;
    int base = S[b * NBK];
    int next = (b < NBK - 1) ? S[(b + 1) * NBK] : NE;
    int cntb = next - base;
    hist[t] = 0;
    __syncthreads();
    for (int i = t; i < cntb; i += 256) atomicAdd(&hist[tmp[base + i] >> 16], 1);
    __syncthreads();
    int v = hist[t];
    off[t] = v; __syncthreads();
    for (int o = 1; o < 256; o <<= 1) {
        int u = (t >= o) ? off[t - o] : 0;
        __syncthreads(); off[t] += u; __syncthreads();
    }
    int excl = off[t] - v;
    int node = b * 256 + t;
    if (node <= NN) rowptr[node] = base + excl;
    cur[t] = excl;
    __syncthreads();
    for (int i = t; i < cntb; i += 256) {
        int e = tmp[base + i];
        int p = atomicAdd(&cur[e >> 16], 1);
        colsrc[base + p] = e & 0xffff;
    }
}

// ---------------- XCD-sliced edge aggregation ----------------
// slice = blockIdx & 3 -> lands on XCD pair {s, s+4} (round-robin blockIdx%8 -> XCD).
// Each 16-lane group owns one node; 32 features (64B = 1 cache line) per edge.
// Per-XCD L2 working set: 3.2 MB slice table (fits 4 MB L2).
__global__ __launch_bounds__(256) void aggs_k(const unsigned short* __restrict__ feat,
                                              const int* __restrict__ rowptr,
                                              const int* __restrict__ colsrc,
                                              unsigned short* __restrict__ outp) {
    const int slice = blockIdx.x & 3;
    const int gid = threadIdx.x >> 4;             // 16 groups per block
    const int l16 = threadIdx.x & 15;
    const int node = (blockIdx.x >> 2) * 16 + gid;
    const int fo = slice * 32 + l16 * 2;
    const int beg = rowptr[node], end = rowptr[node + 1];
    float ax = 0.f, ay = 0.f;
    int e = beg;
    for (; e + 8 <= end; e += 8) {
        int c[8];
#pragma unroll
        for (int i = 0; i < 8; ++i) c[i] = colsrc[e + i];
        unsigned int v[8];
#pragma unroll
        for (int i = 0; i < 8; ++i)
            v[i] = *(const unsigned int*)&feat[(size_t)c[i] * 128 + fo];
#pragma unroll
        for (int i = 0; i < 8; ++i) { ax += bflo(v[i]); ay += bfhi(v[i]); }
    }
    for (; e < end; ++e) {
        unsigned int v = *(const unsigned int*)&feat[(size_t)colsrc[e] * 128 + fo];
        ax += bflo(v); ay += bfhi(v);
    }
    unsigned int p = ((unsigned int)f2bf(ay) << 16) | f2bf(ax);
    *(unsigned int*)&outp[(size_t)node * 128 + fo] = p;
}

// fused L3 epilogue: v = elu(agg(y)[n] + r[n] + b3) per node, sliced like aggs_k
__global__ __launch_bounds__(256) void aggfs_k(const unsigned short* __restrict__ y,
                                               const unsigned short* __restrict__ rr,
                                               const float* __restrict__ b3,
                                               const int* __restrict__ rowptr,
                                               const int* __restrict__ colsrc,
                                               unsigned short* __restrict__ outp) {
    const int slice = blockIdx.x & 3;
    const int gid = threadIdx.x >> 4;
    const int l16 = threadIdx.x & 15;
    const int node = (blockIdx.x >> 2) * 16 + gid;
    const int fo = slice * 32 + l16 * 2;
    const int beg = rowptr[node], end = rowptr[node + 1];
    float ax = 0.f, ay = 0.f;
    int e = beg;
    for (; e + 8 <= end; e += 8) {
        int c[8];
#pragma unroll
        for (int i = 0; i < 8; ++i) c[i] = colsrc[e + i];
        unsigned int v[8];
#pragma unroll
        for (int i = 0; i < 8; ++i)
            v[i] = *(const unsigned int*)&y[(size_t)c[i] * 128 + fo];
#pragma unroll
        for (int i = 0; i < 8; ++i) { ax += bflo(v[i]); ay += bfhi(v[i]); }
    }
    for (; e < end; ++e) {
        unsigned int v = *(const unsigned int*)&y[(size_t)colsrc[e] * 128 + fo];
        ax += bflo(v); ay += bfhi(v);
    }
    unsigned int rv = *(const unsigned int*)&rr[(size_t)node * 128 + fo];
    float2 bb = *(const float2*)&b3[fo];
    float vx = ax + bflo(rv) + bb.x;
    float vy = ay + bfhi(rv) + bb.y;
    vx = vx > 0.f ? vx : (__expf(vx) - 1.f);
    vy = vy > 0.f ? vy : (__expf(vy) - 1.f);
    unsigned int p = ((unsigned int)f2bf(vy) << 16) | f2bf(vx);
    *(unsigned int*)&outp[(size_t)node * 128 + fo] = p;
}

// ---------------- 64x128 MFMA GEMM (L1), double-buffered LDS ----------------
template <int MT, int KA, int N, bool TWO, bool BIAS, bool ELU>
__global__ __launch_bounds__(256) void gemm_k(const unsigned short* __restrict__ A1,
                                              const unsigned short* __restrict__ A2,
                                              const unsigned short* __restrict__ WT,
                                              const float* __restrict__ bias,
                                              unsigned short* __restrict__ Cout) {
    constexpr int KTOT = TWO ? 2 * KA : KA;
    constexpr int NSTEP = KTOT / 32;
    constexpr int MI = MT / 32;
    constexpr int LA = MT / 64;          // A stage instrs per thread
    constexpr int LB = N / 64;           // B stage instrs per thread
    __shared__ __attribute__((aligned(16))) unsigned short As[2][MT * 32];
    __shared__ __attribute__((aligned(16))) unsigned short Bs[2][N * 32];
    const int t = threadIdx.x;
    const int wv = t >> 6, lane = t & 63;
    const int qd = lane >> 4, l16 = lane & 15;
    const int m0 = blockIdx.x * MT;
    const int mh = (wv & 1) * (MT / 2), nh = (wv >> 1) * 64;
    const int srow = lane >> 2;
    const int skk  = (lane & 3) * 8;

    f32x4 acc[MI][4] = {};

    auto stage = [&](int k0, int buf) {
        const unsigned short* Abase = (TWO && k0 >= KA) ? (A2 + (k0 - KA)) : (A1 + k0);
#pragma unroll
        for (int i = 0; i < LA; ++i) {
            int chunk = wv * LA + i;
            const unsigned short* g = Abase + (size_t)(m0 + chunk * 16 + srow) * KA + skk;
            GLD_LDS16(g, &As[buf][chunk * 512]);
        }
        const unsigned short* Wbase = WT + k0;
#pragma unroll
        for (int i = 0; i < LB; ++i) {
            int chunk = wv * LB + i;
            const unsigned short* g = Wbase + (size_t)(chunk * 16 + srow) * KTOT + skk;
            GLD_LDS16(g, &Bs[buf][chunk * 512]);
        }
    };

    stage(0, 0);
    for (int s = 0; s < NSTEP; ++s) {
        const int cur = s & 1;
        if (s + 1 < NSTEP) {
            stage((s + 1) * 32, cur ^ 1);
            asm volatile("s_waitcnt vmcnt(%0)" :: "i"(LA + LB) : "memory");
        } else {
            asm volatile("s_waitcnt vmcnt(0)" ::: "memory");
        }
        __builtin_amdgcn_s_barrier();
        asm volatile("" ::: "memory");
        bf16x8 af[MI], bfr[4];
#pragma unroll
        for (int mi = 0; mi < MI; ++mi)
            af[mi] = *(const bf16x8*)&As[cur][(mh + mi * 16 + l16) * 32 + qd * 8];
#pragma unroll
        for (int ni = 0; ni < 4; ++ni)
            bfr[ni] = *(const bf16x8*)&Bs[cur][(nh + ni * 16 + l16) * 32 + qd * 8];
#pragma unroll
        for (int mi = 0; mi < MI; ++mi)
#pragma unroll
            for (int ni = 0; ni < 4; ++ni)
                acc[mi][ni] = __builtin_amdgcn_mfma_f32_16x16x32_bf16(
                    af[mi], bfr[ni], acc[mi][ni], 0, 0, 0);
        asm volatile("" ::: "memory");
        __builtin_amdgcn_s_barrier();
    }

#pragma unroll
    for (int mi = 0; mi < MI; ++mi)
#pragma unroll
        for (int ni = 0; ni < 4; ++ni)
#pragma unroll
            for (int r = 0; r < 4; ++r) {
                int mm = m0 + mh + mi * 16 + qd * 4 + r;
                if (mm < NN) {
                    int nn = nh + ni * 16 + l16;
                    float v = acc[mi][ni][r];
                    if (BIAS) v += bias[nn];
                    if (ELU) v = v > 0.f ? v : (__expf(v) - 1.f);
                    Cout[(size_t)mm * N + nn] = f2bf(v);
                }
            }
}

// ---------------- 64x256 single-pass GEMM (L2 / L3), double-buffered ----------------
template <int KA, bool TWO, bool BIAS, bool ELU, bool SPLIT>
__global__ __launch_bounds__(256) void gemm256_k(const unsigned short* __restrict__ A1,
                                                 const unsigned short* __restrict__ A2,
                                                 const unsigned short* __restrict__ WT,
                                                 const float* __restrict__ bias,
                                                 unsigned short* __restrict__ Cout,
                                                 unsigned short* __restrict__ Cout2) {
    constexpr int KTOT = TWO ? 2 * KA : KA;
    constexpr int NSTEP = KTOT / 32;
    __shared__ __attribute__((aligned(16))) unsigned short As[2][64 * 32];
    __shared__ __attribute__((aligned(16))) unsigned short Bs[2][256 * 32];
    const int t = threadIdx.x;
    const int wv = t >> 6, lane = t & 63;
    const int qd = lane >> 4, l16 = lane & 15;
    const int m0 = blockIdx.x * 64;
    const int srow = lane >> 2;
    const int skk  = (lane & 3) * 8;

    f32x4 acc[4][4] = {};

    auto stage = [&](int k0, int buf) {
        const unsigned short* Abase = (TWO && k0 >= KA) ? (A2 + (k0 - KA)) : (A1 + k0);
        {
            const unsigned short* g = Abase + (size_t)(m0 + wv * 16 + srow) * KA + skk;
            GLD_LDS16(g, &As[buf][wv * 512]);
        }
        const unsigned short* Wbase = WT + k0;
#pragma unroll
        for (int i = 0; i < 4; ++i) {
            int chunk = wv * 4 + i;
            const unsigned short* g = Wbase + (size_t)(chunk * 16 + srow) * KTOT + skk;
            GLD_LDS16(g, &Bs[buf][chunk * 512]);
        }
    };

    stage(0, 0);
    for (int s = 0; s < NSTEP; ++s) {
        const int cur = s & 1;
        if (s + 1 < NSTEP) {
            stage((s + 1) * 32, cur ^ 1);
            asm volatile("s_waitcnt vmcnt(%0)" :: "i"(5) : "memory");
        } else {
            asm volatile("s_waitcnt vmcnt(0)" ::: "memory");
        }
        __builtin_amdgcn_s_barrier();
        asm volatile("" ::: "memory");
        bf16x8 af[4], bfr[4];
#pragma unroll
        for (int mi = 0; mi < 4; ++mi)
            af[mi] = *(const bf16x8*)&As[cur][(mi * 16 + l16) * 32 + qd * 8];
#pragma unroll
        for (int ni = 0; ni < 4; ++ni)
            bfr[ni] = *(const bf16x8*)&Bs[cur][(wv * 64 + ni * 16 + l16) * 32 + qd * 8];
#pragma unroll
        for (int mi = 0; mi < 4; ++mi)
#pragma unroll
            for (int ni = 0; ni < 4; ++ni)
                acc[mi][ni] = __builtin_amdgcn_mfma_f32_16x16x32_bf16(
                    af[mi], bfr[ni], acc[mi][ni], 0, 0, 0);
        asm volatile("" ::: "memory");
        __builtin_amdgcn_s_barrier();
    }

#pragma unroll
    for (int mi = 0; mi < 4; ++mi)
#pragma unroll
        for (int ni = 0; ni < 4; ++ni)
#pragma unroll
            for (int r = 0; r < 4; ++r) {
                int mm = m0 + mi * 16 + qd * 4 + r;
                if (mm < NN) {
                    int nn = wv * 64 + ni * 16 + l16;
                    float v = acc[mi][ni][r];
                    if (BIAS) v += bias[nn];
                    if (ELU) v = v > 0.f ? v : (__expf(v) - 1.f);
                    unsigned short b = f2bf(v);
                    if (SPLIT) {
                        unsigned short* dst = (nn < 128) ? Cout : Cout2;
                        dst[(size_t)mm * 128 + (nn & 127)] = b;
                    } else {
                        Cout[(size_t)mm * 256 + nn] = b;
                    }
                }
            }
}

// ---------------- segmented graph-sum + divide ----------------
__global__ __launch_bounds__(256) void sum_k(const unsigned short* __restrict__ vals,
                                             const int* __restrict__ batch,
                                             float* __restrict__ outsum) {
    const int CH = 25;                        // 2000 * 25 = 50000
    int wv = threadIdx.x >> 6, lane = threadIdx.x & 63;
    int n0 = (blockIdx.x * 4 + wv) * CH;
    int g = batch[n0];
    float ax = 0.f, ay = 0.f;
    for (int i = 0; i < CH; ++i) {
        int n = n0 + i;
        int gn = batch[n];
        if (gn != g) {
            unsafeAtomicAdd(&outsum[(size_t)g * 128 + lane * 2], ax);
            unsafeAtomicAdd(&outsum[(size_t)g * 128 + lane * 2 + 1], ay);
            ax = 0.f; ay = 0.f; g = gn;
        }
        unsigned int v = *(const unsigned int*)&vals[(size_t)n * 128 + lane * 2];
        ax += bflo(v); ay += bfhi(v);
    }
    unsafeAtomicAdd(&outsum[(size_t)g * 128 + lane * 2], ax);
    unsafeAtomicAdd(&outsum[(size_t)g * 128 + lane * 2 + 1], ay);
}

__global__ void divide_k(const int* __restrict__ bounds, float* __restrict__ out) {
    int i = blockIdx.x * 256 + threadIdx.x;
    if (i < NG * 128) {
        int g = i >> 7;
        float c = (float)(bounds[g + 1] - bounds[g]);
        out[i] /= fmaxf(c, 1.f);
    }
}

extern "C" void kernel_launch(void* const* d_in, const int* in_sizes, int n_in,
                              void* d_out, int out_size, void* d_ws, size_t ws_size,
                              hipStream_t stream) {
    const float* x       = (const float*)d_in[0];
    const int*   ei      = (const int*)d_in[1];
    const int*   batch   = (const int*)d_in[2];
    const float* w_rel1  = (const float*)d_in[3];
    const float* b_rel1  = (const float*)d_in[4];
    const float* w_root1 = (const float*)d_in[5];
    const float* w_rel2  = (const float*)d_in[6];
    const float* b_rel2  = (const float*)d_in[7];
    const float* w_root2 = (const float*)d_in[8];
    const float* w_rel3  = (const float*)d_in[9];
    const float* b_rel3  = (const float*)d_in[10];
    const float* w_root3 = (const float*)d_in[11];
    const int* esrc = ei;
    const int* edst = ei + NE;

    unsigned short* Ab = (unsigned short*)d_ws;          // [NNP,128] agg out / y
    unsigned short* Bb = Ab + (size_t)NNP * 128;         // [NNP,128] h1 / r
    unsigned short* Cb = Bb + (size_t)NNP * 128;         // [NNP,256] h2 ; front = node vals
    unsigned short* xb = Cb + (size_t)NNP * 256;         // [NNP,128] x in bf16
    unsigned short* W1T = xb + (size_t)NNP * 128;        // [128,256]
    unsigned short* W2T = W1T + 128 * 256;               // [256,256]
    unsigned short* W3T = W2T + 256 * 256;               // [256,256]
    int* rowptr = (int*)(W3T + 256 * 256);               // NN+1
    int* colsrc = rowptr + (NN + 1);                     // NE
    int* tmp    = colsrc + NE;                           // NE
    int* H      = tmp + NE;                              // TOTH
    int* S      = H + TOTH;                              // TOTH
    int* hb     = S + TOTH;                              // 256
    int* bounds = hb + 256;                              // NG+1
    float* outp = (float*)d_out;

    // --- front (setup + hist + bounds/zero in one dispatch), then scan chain ---
    front_k<<<SBLK + NBK + 1, 256, 0, stream>>>(
        x, w_rel1, w_root1, w_rel2, w_root2, w_rel3, w_root3, edst, batch,
        xb, W1T, W2T, W3T, H, bounds, outp);
    hsum_k<<<NBH, 256, 0, stream>>>(H, hb);
    happly_k<<<NBH, 256, 0, stream>>>(H, hb, S);
    scatter_k<<<NBK, 256, 0, stream>>>(esrc, edst, S, tmp);
    csr_k<<<NBK, 256, 0, stream>>>(tmp, S, rowptr, colsrc);

    // L1: h1 = elu([agg(x) | x] @ W1 + b1)    -> Bb
    aggs_k<<<AGB, 256, 0, stream>>>(xb, rowptr, colsrc, Ab);
    gemm_k<64, 128, 128, true, true, true>
        <<<NNP / 64, 256, 0, stream>>>(Ab, xb, W1T, b_rel1, Bb);

    // L2: h2 = elu([agg(h1) | h1] @ W2 + b2)  -> Cb   (single-pass N=256)
    aggs_k<<<AGB, 256, 0, stream>>>(Bb, rowptr, colsrc, Ab);
    gemm256_k<128, true, true, true, false>
        <<<NNP / 64, 256, 0, stream>>>(Ab, Bb, W2T, b_rel2, Cb, nullptr);

    // L3: y = h2@w_rel3 -> Ab, r = h2@w_root3 -> Bb (one dispatch, split outputs)
    gemm256_k<256, false, false, false, true>
        <<<NNP / 64, 256, 0, stream>>>(Cb, nullptr, W3T, nullptr, Ab, Bb);

    // fused gather+elu per node, then segmented graph-mean
    aggfs_k<<<AGB, 256, 0, stream>>>(Ab, Bb, b_rel3, rowptr, colsrc, Cb);
    sum_k<<<NN / 100, 256, 0, stream>>>(Cb, batch, outp);
    divide_k<<<(NG * 128 + 255) / 256, 256, 0, stream>>>(bounds, outp);
}

// Round 2
// 299.424 us; speedup vs baseline: 1.2118x; 1.2118x over previous
//
#include <hip/hip_runtime.h>
#include <math.h>

#define NN 50000
#define NNP 50048        // 391*128, padded row count for GEMM staging
#define NE 800000
#define NG 64
#define NBK 196          // buckets of 256 nodes
#define ECH 4082         // edges per hist/scatter block
#define TOTH (NBK * NBK) // 38416
#define NBH 151          // ceil(TOTH/256)
#define SBLK 6890        // setup blocks: (NN*32+163840)/256
#define SWORK (NN * 32 + 163840)

typedef __attribute__((ext_vector_type(8))) __bf16 bf16x8;
typedef __attribute__((ext_vector_type(4))) float f32x4;

__device__ inline unsigned short f2bf(float f) {
    unsigned int u = __float_as_uint(f);
    u += 0x7fffu + ((u >> 16) & 1u);   // round-to-nearest-even
    return (unsigned short)(u >> 16);
}
__device__ inline float bflo(unsigned int v) { return __uint_as_float(v << 16); }
__device__ inline float bfhi(unsigned int v) { return __uint_as_float(v & 0xffff0000u); }
__device__ inline float bfs(unsigned short v) { return __uint_as_float((unsigned int)v << 16); }

#define GLD_LDS16(g, l)                                                          \
    __builtin_amdgcn_global_load_lds(                                            \
        (const __attribute__((address_space(1))) unsigned int*)(g),              \
        (__attribute__((address_space(3))) unsigned int*)(l), 16, 0, 0)

// ------- front: x->bf16 + weight transposes + dst-histogram + bounds + out-zero ----
__global__ __launch_bounds__(256) void front_k(const float* __restrict__ x,
                                               const float* __restrict__ wr1,
                                               const float* __restrict__ wo1,
                                               const float* __restrict__ wr2,
                                               const float* __restrict__ wo2,
                                               const float* __restrict__ wr3,
                                               const float* __restrict__ wo3,
                                               const int* __restrict__ edst,
                                               const int* __restrict__ batch,
                                               unsigned short* __restrict__ xb,
                                               unsigned short* __restrict__ W1T,
                                               unsigned short* __restrict__ W2T,
                                               unsigned short* __restrict__ W3T,
                                               int* __restrict__ H,
                                               int* __restrict__ bounds,
                                               float* __restrict__ outp) {
    const int b = blockIdx.x, t = threadIdx.x;
    if (b < SBLK) {
        int id = b * 256 + t;
        if (id < NN * 32) {                       // x: 4 floats per thread
            float4 v = ((const float4*)x)[id];
            unsigned int p0 = ((unsigned int)f2bf(v.y) << 16) | f2bf(v.x);
            unsigned int p1 = ((unsigned int)f2bf(v.w) << 16) | f2bf(v.z);
            ((uint2*)xb)[id] = make_uint2(p0, p1);
            return;
        }
        int w = id - NN * 32;
        if (w < 32768) {
            int n = w >> 8, k = w & 255;
            W1T[w] = f2bf((k < 128) ? wr1[k * 128 + n] : wo1[(k - 128) * 128 + n]);
        } else if (w < 98304) {
            int j = w - 32768; int n = j >> 8, k = j & 255;
            W2T[j] = f2bf((k < 128) ? wr2[k * 256 + n] : wo2[(k - 128) * 256 + n]);
        } else if (w < 163840) {
            int j = w - 98304; int n = j >> 8, k = j & 255;
            W3T[j] = f2bf((n < 128) ? wr3[k * 128 + n] : wo3[k * 128 + (n - 128)]);
        }
        return;
    }
    if (b < SBLK + NBK) {                         // histogram chunk
        __shared__ int h[NBK];
        int k = b - SBLK;
        if (t < NBK) h[t] = 0;
        __syncthreads();
        int e0 = k * ECH, e1 = min(NE, e0 + ECH);
        for (int e = e0 + t; e < e1; e += 256) atomicAdd(&h[edst[e] >> 8], 1);
        __syncthreads();
        if (t < NBK) H[t * NBK + k] = h[t];       // bucket-major layout
        return;
    }
    // last block: graph bounds + zero output accumulator
    if (t <= NG) {
        int g = t, lo = 0, hi = NN;
        while (lo < hi) { int mid = (lo + hi) >> 1; if (batch[mid] < g) lo = mid + 1; else hi = mid; }
        bounds[g] = lo;
    }
    for (int i = t; i < NG * 128; i += 256) outp[i] = 0.f;
}

// ---------------- hierarchical scan of H ----------------
__global__ __launch_bounds__(256) void hsum_k(const int* __restrict__ H,
                                              int* __restrict__ hb) {
    int i = blockIdx.x * 256 + threadIdx.x;
    int v = (i < TOTH) ? H[i] : 0;
    for (int off = 32; off; off >>= 1) v += __shfl_xor(v, off, 64);
    __shared__ int ws[4];
    if ((threadIdx.x & 63) == 0) ws[threadIdx.x >> 6] = v;
    __syncthreads();
    if (threadIdx.x == 0) hb[blockIdx.x] = ws[0] + ws[1] + ws[2] + ws[3];
}

// folded: each block computes its own chunk offset (reduce hb[0..c)) + local scan
__global__ __launch_bounds__(256) void happly_k(const int* __restrict__ H,
                                                const int* __restrict__ hb,
                                                int* __restrict__ S) {
    __shared__ int s[256], ws[4], choff;
    const int t = threadIdx.x, c = blockIdx.x;
    {   // chunk offset = sum of hb[0..c)
        int v = (t < c) ? hb[t] : 0;              // c <= 150 < 256
        for (int off = 32; off; off >>= 1) v += __shfl_xor(v, off, 64);
        if ((t & 63) == 0) ws[t >> 6] = v;
        __syncthreads();
        if (t == 0) choff = ws[0] + ws[1] + ws[2] + ws[3];
        __syncthreads();
    }
    int i = c * 256 + t;
    int v = (i < TOTH) ? H[i] : 0;
    s[t] = v; __syncthreads();
    for (int off = 1; off < 256; off <<= 1) {
        int u = (t >= off) ? s[t - off] : 0;
        __syncthreads(); s[t] += u; __syncthreads();
    }
    if (i < TOTH) S[i] = choff + s[t] - v;
}

__global__ __launch_bounds__(256) void scatter_k(const int* __restrict__ src,
                                                 const int* __restrict__ dst,
                                                 const int* __restrict__ S,
                                                 int* __restrict__ tmp) {
    __shared__ int cur[NBK];
    int t = threadIdx.x, k = blockIdx.x;
    if (t < NBK) cur[t] = S[t * NBK + k];
    __syncthreads();
    int e0 = k * ECH, e1 = min(NE, e0 + ECH);
    for (int e = e0 + t; e < e1; e += 256) {
        int d = dst[e];
        int p = atomicAdd(&cur[d >> 8], 1);
        tmp[p] = ((d & 255) << 16) | src[e];
    }
}

__global__ __launch_bounds__(256) void csr_k(const int* __restrict__ tmp,
                                             const int* __restrict__ S,
                                             int* __restrict__ rowptr,
                                             int* __restrict__ colsrc) {
    __shared__ int hist[256], off[256], cur[256];
    int t = threadIdx.x, b = blockIdx.x;
    int base = S[b * NBK];
    int next = (b < NBK - 1) ? S[(b + 1) * NBK] : NE;
    int cntb = next - base;
    hist[t] = 0;
    __syncthreads();
    for (int i = t; i < cntb; i += 256) atomicAdd(&hist[tmp[base + i] >> 16], 1);
    __syncthreads();
    int v = hist[t];
    off[t] = v; __syncthreads();
    for (int o = 1; o < 256; o <<= 1) {
        int u = (t >= o) ? off[t - o] : 0;
        __syncthreads(); off[t] += u; __syncthreads();
    }
    int excl = off[t] - v;
    int node = b * 256 + t;
    if (node <= NN) rowptr[node] = base + excl;
    cur[t] = excl;
    __syncthreads();
    for (int i = t; i < cntb; i += 256) {
        int e = tmp[base + i];
        int p = atomicAdd(&cur[e >> 16], 1);
        colsrc[base + p] = e & 0xffff;
    }
}

// ---------------- edge aggregation: one wave per node, 2 edges per load instr ----
// lane = 32*half + l32; lane loads uint2 (4 features) of edge e+half at byte
// offset l32*8 within the 256B row -> each load instr covers 2 contiguous 256B
// rows. 16-edge main block = 8 load instrs = 64 cache lines in flight per wave.
__global__ __launch_bounds__(256) void aggb_k(const unsigned short* __restrict__ feat,
                                              const int* __restrict__ rowptr,
                                              const int* __restrict__ colsrc,
                                              unsigned short* __restrict__ outp) {
    const int node = __builtin_amdgcn_readfirstlane((int)(blockIdx.x * 4 + (threadIdx.x >> 6)));
    const int lane = threadIdx.x & 63;
    const int half = lane >> 5, l32 = lane & 31;
    const int beg = rowptr[node], end = rowptr[node + 1];
    float a0 = 0.f, a1 = 0.f, a2 = 0.f, a3 = 0.f;
    int e = beg;
    for (; e + 16 <= end; e += 16) {
        int c[8]; uint2 v[8];
#pragma unroll
        for (int i = 0; i < 8; ++i) c[i] = colsrc[e + 2 * i + half];
#pragma unroll
        for (int i = 0; i < 8; ++i)
            v[i] = *(const uint2*)&feat[(size_t)c[i] * 128 + l32 * 4];
#pragma unroll
        for (int i = 0; i < 8; ++i) {
            a0 += bflo(v[i].x); a1 += bfhi(v[i].x);
            a2 += bflo(v[i].y); a3 += bfhi(v[i].y);
        }
    }
    for (; e + 4 <= end; e += 4) {
        int c[2]; uint2 v[2];
#pragma unroll
        for (int i = 0; i < 2; ++i) c[i] = colsrc[e + 2 * i + half];
#pragma unroll
        for (int i = 0; i < 2; ++i)
            v[i] = *(const uint2*)&feat[(size_t)c[i] * 128 + l32 * 4];
#pragma unroll
        for (int i = 0; i < 2; ++i) {
            a0 += bflo(v[i].x); a1 += bfhi(v[i].x);
            a2 += bflo(v[i].y); a3 += bfhi(v[i].y);
        }
    }
    if (e + 2 <= end) {
        int c = colsrc[e + half];
        uint2 v = *(const uint2*)&feat[(size_t)c * 128 + l32 * 4];
        a0 += bflo(v.x); a1 += bfhi(v.x); a2 += bflo(v.y); a3 += bfhi(v.y);
        e += 2;
    }
    if (e < end && half == 0) {
        int c = colsrc[e];
        uint2 v = *(const uint2*)&feat[(size_t)c * 128 + l32 * 4];
        a0 += bflo(v.x); a1 += bfhi(v.x); a2 += bflo(v.y); a3 += bfhi(v.y);
    }
    a0 += __shfl_xor(a0, 32, 64);
    a1 += __shfl_xor(a1, 32, 64);
    a2 += __shfl_xor(a2, 32, 64);
    a3 += __shfl_xor(a3, 32, 64);
    if (half == 0) {
        unsigned int p0 = ((unsigned int)f2bf(a1) << 16) | f2bf(a0);
        unsigned int p1 = ((unsigned int)f2bf(a3) << 16) | f2bf(a2);
        *(uint2*)&outp[(size_t)node * 128 + l32 * 4] = make_uint2(p0, p1);
    }
}

// fused L3 epilogue: v = elu(agg(y)[n] + r[n] + b3) per node (same structure)
__global__ __launch_bounds__(256) void aggf_k(const unsigned short* __restrict__ y,
                                              const unsigned short* __restrict__ rr,
                                              const float* __restrict__ b3,
                                              const int* __restrict__ rowptr,
                                              const int* __restrict__ colsrc,
                                              unsigned short* __restrict__ outp) {
    const int node = __builtin_amdgcn_readfirstlane((int)(blockIdx.x * 4 + (threadIdx.x >> 6)));
    const int lane = threadIdx.x & 63;
    const int half = lane >> 5, l32 = lane & 31;
    const int beg = rowptr[node], end = rowptr[node + 1];
    float a0 = 0.f, a1 = 0.f, a2 = 0.f, a3 = 0.f;
    int e = beg;
    for (; e + 16 <= end; e += 16) {
        int c[8]; uint2 v[8];
#pragma unroll
        for (int i = 0; i < 8; ++i) c[i] = colsrc[e + 2 * i + half];
#pragma unroll
        for (int i = 0; i < 8; ++i)
            v[i] = *(const uint2*)&y[(size_t)c[i] * 128 + l32 * 4];
#pragma unroll
        for (int i = 0; i < 8; ++i) {
            a0 += bflo(v[i].x); a1 += bfhi(v[i].x);
            a2 += bflo(v[i].y); a3 += bfhi(v[i].y);
        }
    }
    for (; e + 4 <= end; e += 4) {
        int c[2]; uint2 v[2];
#pragma unroll
        for (int i = 0; i < 2; ++i) c[i] = colsrc[e + 2 * i + half];
#pragma unroll
        for (int i = 0; i < 2; ++i)
            v[i] = *(const uint2*)&y[(size_t)c[i] * 128 + l32 * 4];
#pragma unroll
        for (int i = 0; i < 2; ++i) {
            a0 += bflo(v[i].x); a1 += bfhi(v[i].x);
            a2 += bflo(v[i].y); a3 += bfhi(v[i].y);
        }
    }
    if (e + 2 <= end) {
        int c = colsrc[e + half];
        uint2 v = *(const uint2*)&y[(size_t)c * 128 + l32 * 4];
        a0 += bflo(v.x); a1 += bfhi(v.x); a2 += bflo(v.y); a3 += bfhi(v.y);
        e += 2;
    }
    if (e < end && half == 0) {
        int c = colsrc[e];
        uint2 v = *(const uint2*)&y[(size_t)c * 128 + l32 * 4];
        a0 += bflo(v.x); a1 += bfhi(v.x); a2 += bflo(v.y); a3 += bfhi(v.y);
    }
    a0 += __shfl_xor(a0, 32, 64);
    a1 += __shfl_xor(a1, 32, 64);
    a2 += __shfl_xor(a2, 32, 64);
    a3 += __shfl_xor(a3, 32, 64);
    if (half == 0) {
        uint2 rv = *(const uint2*)&rr[(size_t)node * 128 + l32 * 4];
        float4 bb = *(const float4*)&b3[l32 * 4];
        float v0 = a0 + bflo(rv.x) + bb.x;
        float v1 = a1 + bfhi(rv.x) + bb.y;
        float v2 = a2 + bflo(rv.y) + bb.z;
        float v3 = a3 + bfhi(rv.y) + bb.w;
        v0 = v0 > 0.f ? v0 : (__expf(v0) - 1.f);
        v1 = v1 > 0.f ? v1 : (__expf(v1) - 1.f);
        v2 = v2 > 0.f ? v2 : (__expf(v2) - 1.f);
        v3 = v3 > 0.f ? v3 : (__expf(v3) - 1.f);
        unsigned int p0 = ((unsigned int)f2bf(v1) << 16) | f2bf(v0);
        unsigned int p1 = ((unsigned int)f2bf(v3) << 16) | f2bf(v2);
        *(uint2*)&outp[(size_t)node * 128 + l32 * 4] = make_uint2(p0, p1);
    }
}

// ---------------- 64x128 MFMA GEMM (L1), double-buffered LDS ----------------
template <int MT, int KA, int N, bool TWO, bool BIAS, bool ELU>
__global__ __launch_bounds__(256) void gemm_k(const unsigned short* __restrict__ A1,
                                              const unsigned short* __restrict__ A2,
                                              const unsigned short* __restrict__ WT,
                                              const float* __restrict__ bias,
                                              unsigned short* __restrict__ Cout) {
    constexpr int KTOT = TWO ? 2 * KA : KA;
    constexpr int NSTEP = KTOT / 32;
    constexpr int MI = MT / 32;
    constexpr int LA = MT / 64;          // A stage instrs per thread
    constexpr int LB = N / 64;           // B stage instrs per thread
    __shared__ __attribute__((aligned(16))) unsigned short As[2][MT * 32];
    __shared__ __attribute__((aligned(16))) unsigned short Bs[2][N * 32];
    const int t = threadIdx.x;
    const int wv = t >> 6, lane = t & 63;
    const int qd = lane >> 4, l16 = lane & 15;
    const int m0 = blockIdx.x * MT;
    const int mh = (wv & 1) * (MT / 2), nh = (wv >> 1) * 64;
    const int srow = lane >> 2;
    const int skk  = (lane & 3) * 8;

    f32x4 acc[MI][4] = {};

    auto stage = [&](int k0, int buf) {
        const unsigned short* Abase = (TWO && k0 >= KA) ? (A2 + (k0 - KA)) : (A1 + k0);
#pragma unroll
        for (int i = 0; i < LA; ++i) {
            int chunk = wv * LA + i;
            const unsigned short* g = Abase + (size_t)(m0 + chunk * 16 + srow) * KA + skk;
            GLD_LDS16(g, &As[buf][chunk * 512]);
        }
        const unsigned short* Wbase = WT + k0;
#pragma unroll
        for (int i = 0; i < LB; ++i) {
            int chunk = wv * LB + i;
            const unsigned short* g = Wbase + (size_t)(chunk * 16 + srow) * KTOT + skk;
            GLD_LDS16(g, &Bs[buf][chunk * 512]);
        }
    };

    stage(0, 0);
    for (int s = 0; s < NSTEP; ++s) {
        const int cur = s & 1;
        if (s + 1 < NSTEP) {
            stage((s + 1) * 32, cur ^ 1);
            asm volatile("s_waitcnt vmcnt(%0)" :: "i"(LA + LB) : "memory");
        } else {
            asm volatile("s_waitcnt vmcnt(0)" ::: "memory");
        }
        __builtin_amdgcn_s_barrier();
        asm volatile("" ::: "memory");
        bf16x8 af[MI], bfr[4];
#pragma unroll
        for (int mi = 0; mi < MI; ++mi)
            af[mi] = *(const bf16x8*)&As[cur][(mh + mi * 16 + l16) * 32 + qd * 8];
#pragma unroll
        for (int ni = 0; ni < 4; ++ni)
            bfr[ni] = *(const bf16x8*)&Bs[cur][(nh + ni * 16 + l16) * 32 + qd * 8];
#pragma unroll
        for (int mi = 0; mi < MI; ++mi)
#pragma unroll
            for (int ni = 0; ni < 4; ++ni)
                acc[mi][ni] = __builtin_amdgcn_mfma_f32_16x16x32_bf16(
                    af[mi], bfr[ni], acc[mi][ni], 0, 0, 0);
        asm volatile("" ::: "memory");
        __builtin_amdgcn_s_barrier();
    }

#pragma unroll
    for (int mi = 0; mi < MI; ++mi)
#pragma unroll
        for (int ni = 0; ni < 4; ++ni)
#pragma unroll
            for (int r = 0; r < 4; ++r) {
                int mm = m0 + mh + mi * 16 + qd * 4 + r;
                if (mm < NN) {
                    int nn = nh + ni * 16 + l16;
                    float v = acc[mi][ni][r];
                    if (BIAS) v += bias[nn];
                    if (ELU) v = v > 0.f ? v : (__expf(v) - 1.f);
                    Cout[(size_t)mm * N + nn] = f2bf(v);
                }
            }
}

// ---------------- 64x256 single-pass GEMM (L2 / L3), double-buffered ----------------
template <int KA, bool TWO, bool BIAS, bool ELU, bool SPLIT>
__global__ __launch_bounds__(256) void gemm256_k(const unsigned short* __restrict__ A1,
                                                 const unsigned short* __restrict__ A2,
                                                 const unsigned short* __restrict__ WT,
                                                 const float* __restrict__ bias,
                                                 unsigned short* __restrict__ Cout,
                                                 unsigned short* __restrict__ Cout2) {
    constexpr int KTOT = TWO ? 2 * KA : KA;
    constexpr int NSTEP = KTOT / 32;
    __shared__ __attribute__((aligned(16))) unsigned short As[2][64 * 32];
    __shared__ __attribute__((aligned(16))) unsigned short Bs[2][256 * 32];
    const int t = threadIdx.x;
    const int wv = t >> 6, lane = t & 63;
    const int qd = lane >> 4, l16 = lane & 15;
    const int m0 = blockIdx.x * 64;
    const int srow = lane >> 2;
    const int skk  = (lane & 3) * 8;

    f32x4 acc[4][4] = {};

    auto stage = [&](int k0, int buf) {
        const unsigned short* Abase = (TWO && k0 >= KA) ? (A2 + (k0 - KA)) : (A1 + k0);
        {
            const unsigned short* g = Abase + (size_t)(m0 + wv * 16 + srow) * KA + skk;
            GLD_LDS16(g, &As[buf][wv * 512]);
        }
        const unsigned short* Wbase = WT + k0;
#pragma unroll
        for (int i = 0; i < 4; ++i) {
            int chunk = wv * 4 + i;
            const unsigned short* g = Wbase + (size_t)(chunk * 16 + srow) * KTOT + skk;
            GLD_LDS16(g, &Bs[buf][chunk * 512]);
        }
    };

    stage(0, 0);
    for (int s = 0; s < NSTEP; ++s) {
        const int cur = s & 1;
        if (s + 1 < NSTEP) {
            stage((s + 1) * 32, cur ^ 1);
            asm volatile("s_waitcnt vmcnt(%0)" :: "i"(5) : "memory");
        } else {
            asm volatile("s_waitcnt vmcnt(0)" ::: "memory");
        }
        __builtin_amdgcn_s_barrier();
        asm volatile("" ::: "memory");
        bf16x8 af[4], bfr[4];
#pragma unroll
        for (int mi = 0; mi < 4; ++mi)
            af[mi] = *(const bf16x8*)&As[cur][(mi * 16 + l16) * 32 + qd * 8];
#pragma unroll
        for (int ni = 0; ni < 4; ++ni)
            bfr[ni] = *(const bf16x8*)&Bs[cur][(wv * 64 + ni * 16 + l16) * 32 + qd * 8];
#pragma unroll
        for (int mi = 0; mi < 4; ++mi)
#pragma unroll
            for (int ni = 0; ni < 4; ++ni)
                acc[mi][ni] = __builtin_amdgcn_mfma_f32_16x16x32_bf16(
                    af[mi], bfr[ni], acc[mi][ni], 0, 0, 0);
        asm volatile("" ::: "memory");
        __builtin_amdgcn_s_barrier();
    }

#pragma unroll
    for (int mi = 0; mi < 4; ++mi)
#pragma unroll
        for (int ni = 0; ni < 4; ++ni)
#pragma unroll
            for (int r = 0; r < 4; ++r) {
                int mm = m0 + mi * 16 + qd * 4 + r;
                if (mm < NN) {
                    int nn = wv * 64 + ni * 16 + l16;
                    float v = acc[mi][ni][r];
                    if (BIAS) v += bias[nn];
                    if (ELU) v = v > 0.f ? v : (__expf(v) - 1.f);
                    unsigned short b = f2bf(v);
                    if (SPLIT) {
                        unsigned short* dst = (nn < 128) ? Cout : Cout2;
                        dst[(size_t)mm * 128 + (nn & 127)] = b;
                    } else {
                        Cout[(size_t)mm * 256 + nn] = b;
                    }
                }
            }
}

// ---------------- segmented graph-sum + divide ----------------
__global__ __launch_bounds__(256) void sum_k(const unsigned short* __restrict__ vals,
                                             const int* __restrict__ batch,
                                             float* __restrict__ outsum) {
    const int CH = 25;                        // 2000 * 25 = 50000
    int wv = threadIdx.x >> 6, lane = threadIdx.x & 63;
    int n0 = (blockIdx.x * 4 + wv) * CH;
    int g = batch[n0];
    float ax = 0.f, ay = 0.f;
    for (int i = 0; i < CH; ++i) {
        int n = n0 + i;
        int gn = batch[n];
        if (gn != g) {
            unsafeAtomicAdd(&outsum[(size_t)g * 128 + lane * 2], ax);
            unsafeAtomicAdd(&outsum[(size_t)g * 128 + lane * 2 + 1], ay);
            ax = 0.f; ay = 0.f; g = gn;
        }
        unsigned int v = *(const unsigned int*)&vals[(size_t)n * 128 + lane * 2];
        ax += bflo(v); ay += bfhi(v);
    }
    unsafeAtomicAdd(&outsum[(size_t)g * 128 + lane * 2], ax);
    unsafeAtomicAdd(&outsum[(size_t)g * 128 + lane * 2 + 1], ay);
}

__global__ void divide_k(const int* __restrict__ bounds, float* __restrict__ out) {
    int i = blockIdx.x * 256 + threadIdx.x;
    if (i < NG * 128) {
        int g = i >> 7;
        float c = (float)(bounds[g + 1] - bounds[g]);
        out[i] /= fmaxf(c, 1.f);
    }
}

extern "C" void kernel_launch(void* const* d_in, const int* in_sizes, int n_in,
                              void* d_out, int out_size, void* d_ws, size_t ws_size,
                              hipStream_t stream) {
    const float* x       = (const float*)d_in[0];
    const int*   ei      = (const int*)d_in[1];
    const int*   batch   = (const int*)d_in[2];
    const float* w_rel1  = (const float*)d_in[3];
    const float* b_rel1  = (const float*)d_in[4];
    const float* w_root1 = (const float*)d_in[5];
    const float* w_rel2  = (const float*)d_in[6];
    const float* b_rel2  = (const float*)d_in[7];
    const float* w_root2 = (const float*)d_in[8];
    const float* w_rel3  = (const float*)d_in[9];
    const float* b_rel3  = (const float*)d_in[10];
    const float* w_root3 = (const float*)d_in[11];
    const int* esrc = ei;
    const int* edst = ei + NE;

    unsigned short* Ab = (unsigned short*)d_ws;          // [NNP,128] agg out / y
    unsigned short* Bb = Ab + (size_t)NNP * 128;         // [NNP,128] h1 / r
    unsigned short* Cb = Bb + (size_t)NNP * 128;         // [NNP,256] h2 ; front = node vals
    unsigned short* xb = Cb + (size_t)NNP * 256;         // [NNP,128] x in bf16
    unsigned short* W1T = xb + (size_t)NNP * 128;        // [128,256]
    unsigned short* W2T = W1T + 128 * 256;               // [256,256]
    unsigned short* W3T = W2T + 256 * 256;               // [256,256]
    int* rowptr = (int*)(W3T + 256 * 256);               // NN+1
    int* colsrc = rowptr + (NN + 1);                     // NE
    int* tmp    = colsrc + NE;                           // NE
    int* H      = tmp + NE;                              // TOTH
    int* S      = H + TOTH;                              // TOTH
    int* hb     = S + TOTH;                              // 256
    int* bounds = hb + 256;                              // NG+1
    float* outp = (float*)d_out;

    // --- front (setup + hist + bounds/zero in one dispatch), then scan chain ---
    front_k<<<SBLK + NBK + 1, 256, 0, stream>>>(
        x, w_rel1, w_root1, w_rel2, w_root2, w_rel3, w_root3, edst, batch,
        xb, W1T, W2T, W3T, H, bounds, outp);
    hsum_k<<<NBH, 256, 0, stream>>>(H, hb);
    happly_k<<<NBH, 256, 0, stream>>>(H, hb, S);
    scatter_k<<<NBK, 256, 0, stream>>>(esrc, edst, S, tmp);
    csr_k<<<NBK, 256, 0, stream>>>(tmp, S, rowptr, colsrc);

    // L1: h1 = elu([agg(x) | x] @ W1 + b1)    -> Bb
    aggb_k<<<NN / 4, 256, 0, stream>>>(xb, rowptr, colsrc, Ab);
    gemm_k<64, 128, 128, true, true, true>
        <<<NNP / 64, 256, 0, stream>>>(Ab, xb, W1T, b_rel1, Bb);

    // L2: h2 = elu([agg(h1) | h1] @ W2 + b2)  -> Cb   (single-pass N=256)
    aggb_k<<<NN / 4, 256, 0, stream>>>(Bb, rowptr, colsrc, Ab);
    gemm256_k<128, true, true, true, false>
        <<<NNP / 64, 256, 0, stream>>>(Ab, Bb, W2T, b_rel2, Cb, nullptr);

    // L3: y = h2@w_rel3 -> Ab, r = h2@w_root3 -> Bb (one dispatch, split outputs)
    gemm256_k<256, false, false, false, true>
        <<<NNP / 64, 256, 0, stream>>>(Cb, nullptr, W3T, nullptr, Ab, Bb);

    // fused gather+elu per node, then segmented graph-mean
    aggf_k<<<NN / 4, 256, 0, stream>>>(Ab, Bb, b_rel3, rowptr, colsrc, Cb);
    sum_k<<<NN / 100, 256, 0, stream>>>(Cb, batch, outp);
    divide_k<<<(NG * 128 + 255) / 256, 256, 0, stream>>>(bounds, outp);
}